// Round 2
// baseline (1300.014 us; speedup 1.0000x reference)
//
#include <hip/hip_runtime.h>
#include <hip/hip_bf16.h>
#include <hip/hip_fp8.h>
#include <math.h>

// Problem constants: b=4, c=64, h=w=256, WS=8, SHIFT=4, HEADS=4, d=16, hidden=256
// Windows: 32x32 per image * 4 images = 4096; 64 tokens/window.
//
// Workspace layout (peak 160 MB):
//   Cb  bf16 32MB [0,32M)    x3 token-major        written k2, read k3+k5
//   A   fp32 64MB [32,96M)   shortcut token-major  written k1, read k2 (dead after)
//   Bw  bf16 32MB [96,128M)  shifted windows       written k1, read k2 (dead after)
//   D   fp8  64MB [32,96M)   hid image layout      written k3 (aliases A), read k4
//   E   fp8  64MB [96,160M)  hid+conv image layout written k4 (aliases Bw), read k5

__device__ __forceinline__ float gelu_f(float v) {
    return 0.5f * v * (1.0f + erff(v * 0.70710678118654752440f));
}
__device__ __forceinline__ unsigned char f32_to_fp8(float v) {
    __hip_fp8_e4m3 t(v);
    return (unsigned char)t.__x;
}
__device__ __forceinline__ float fp8_to_f32(unsigned char u) {
    __hip_fp8_e4m3 t;
    t.__x = (__hip_fp8_storage_t)u;
    return (float)t;
}

// ---------------------------------------------------------------------------
// Kernel 1: LN1 + transpose. Reads x (b,c,h,w). Writes:
//   A  : shortcut, token-major fp32 [b*65536 tokens][64 ch]
//   Bw : normalized, shifted+window-partitioned bf16 [4096 win][64 tok][64 ch]
// ---------------------------------------------------------------------------
__global__ __launch_bounds__(256) void k_ln1(const float* __restrict__ x,
        const float* __restrict__ w1, const float* __restrict__ b1,
        float* __restrict__ A, __hip_bfloat16* __restrict__ Bw) {
    __shared__ float tile[64 * 65];           // [ch][token]
    __shared__ float red0[256], red1[256];
    __shared__ float muv[64], rsv[64], lw[64], lb[64];
    const int tid = threadIdx.x;
    const int gid = blockIdx.x;
    const int xc = gid & 3, y = (gid >> 2) & 255, b = gid >> 10;
    const int x0 = xc * 64;
    if (tid < 64) { lw[tid] = w1[tid]; lb[tid] = b1[tid]; }

    const float* xb = x + ((size_t)b * 64) * 65536 + y * 256 + x0;
    {
        const int tk = tid & 63, cl = tid >> 6;
        for (int it = 0; it < 16; ++it) {
            int cc = cl + 4 * it;
            tile[cc * 65 + tk] = xb[(size_t)cc * 65536 + tk];   // coalesced
        }
    }
    __syncthreads();
    {
        const int tk = tid & 63, cl = tid >> 6;
        float s = 0.f, s2 = 0.f;
        #pragma unroll
        for (int k = 0; k < 16; ++k) {
            float v = tile[(cl * 16 + k) * 65 + tk];
            s += v; s2 += v * v;
        }
        red0[cl * 64 + tk] = s; red1[cl * 64 + tk] = s2;
    }
    __syncthreads();
    if (tid < 64) {
        float s  = red0[tid] + red0[64 + tid] + red0[128 + tid] + red0[192 + tid];
        float s2 = red1[tid] + red1[64 + tid] + red1[128 + tid] + red1[192 + tid];
        float mu = s * (1.f / 64.f);
        float var = s2 * (1.f / 64.f) - mu * mu;
        muv[tid] = mu; rsv[tid] = rsqrtf(var + 1e-5f);
    }
    __syncthreads();
    const int ch = tid & 63, tl = tid >> 6;
    const int ys = (y + 252) & 255;          // shifted row (roll -4)
    const int wy = ys >> 3, py = ys & 7;
    for (int it = 0; it < 16; ++it) {
        int t = tl + 4 * it;
        float v = tile[ch * 65 + t];         // stride 65 -> free 2-way
        int tok = (b << 16) + y * 256 + x0 + t;
        A[(size_t)tok * 64 + ch] = v;
        float vn = (v - muv[t]) * rsv[t] * lw[ch] + lb[ch];
        int xs = (x0 + t + 252) & 255;
        int wx = xs >> 3, px = xs & 7;
        int widx = (b << 10) + (wy << 5) + wx;
        int pos = (py << 3) + px;
        Bw[((size_t)widx * 64 + pos) * 64 + ch] = __float2bfloat16(vn);
    }
}

// ---------------------------------------------------------------------------
// Kernel 2: windowed attention. One block per window (4096), 256 threads.
// Xl: X(pitch 68) -> Q(pitch 17) -> O(pitch 68)
// Wl: qkvw chunk -> K(pitch 18)[0,4608) + V(pitch 18)[4608,9216)
//                -> projw[0,4096) + P(pitch 68)[4096,8448)
// ---------------------------------------------------------------------------
__global__ __launch_bounds__(256) void k_attn(
        const __hip_bfloat16* __restrict__ Bw,
        const float* __restrict__ qkvw, const float* __restrict__ qkvb,
        const float* __restrict__ rpb,
        const float* __restrict__ projw, const float* __restrict__ projb,
        const float* __restrict__ A, __hip_bfloat16* __restrict__ Cb) {
    __shared__ __align__(16) float Xl[64 * 68];
    __shared__ __align__(16) float Wl[9216];
    __shared__ float rpbl[900];
    const int tid = threadIdx.x;
    const int widx = blockIdx.x;
    const int wib = widx & 1023;
    const int wy = wib >> 5, wx = wib & 31, b = widx >> 10;
    const int t = tid & 63, mb = tid >> 6;

    {   // stage window X (bf16 -> f32) and rpb table
        const __hip_bfloat16* Xg = Bw + (size_t)widx * 4096;
        for (int it = 0; it < 16; ++it) {
            int r = mb + 4 * it;
            Xl[r * 68 + t] = __bfloat162float(Xg[r * 64 + t]);  // coalesced
        }
        for (int i = tid; i < 900; i += 256) rpbl[i] = rpb[i];
    }

    float acc[48];
    #pragma unroll
    for (int a = 0; a < 48; ++a) acc[a] = 0.f;

    // qkv GEMM: acc[a] = row (96*(a/24) + mb + 4*(a%24)) of qkv for token t
    for (int c = 0; c < 2; ++c) {
        __syncthreads();
        for (int i = tid; i < 6144; i += 256) Wl[i] = qkvw[c * 6144 + i];
        __syncthreads();
        for (int k4 = 0; k4 < 16; ++k4) {
            const float4 xv = *(const float4*)&Xl[t * 68 + 4 * k4];
            #pragma unroll
            for (int j = 0; j < 24; ++j) {
                const float4 wv = *(const float4*)&Wl[(mb + 4 * j) * 64 + 4 * k4];
                acc[c * 24 + j] += xv.x * wv.x + xv.y * wv.y + xv.z * wv.z + xv.w * wv.w;
            }
        }
    }
    __syncthreads();   // X and weight chunk dead

    // Scatter Q (scaled, Xl pitch 17), K (Wl pitch 18), V (Wl+4608 pitch 18)
    #pragma unroll
    for (int a = 0; a < 48; ++a) {
        const int c_ = a / 24, jl = a - c_ * 24;
        const int base = 96 * c_ + 4 * jl;       // mb-independent selector
        int m = base + mb;
        float v = acc[a] + qkvb[m];
        int hh = (m >> 4) & 3, dd = m & 15;
        if (base < 64)       Xl[(hh * 64 + t) * 17 + dd] = v * 0.25f;
        else if (base < 128) Wl[(hh * 64 + t) * 18 + dd] = v;
        else                 Wl[4608 + (hh * 64 + t) * 18 + dd] = v;
    }
    __syncthreads();

    // Scores + bias + mask + softmax. wave = head, lane = query token.
    const int h = mb, i = t;
    float qr[16];
    #pragma unroll
    for (int dd = 0; dd < 16; ++dd) qr[dd] = Xl[(h * 64 + i) * 17 + dd];
    const int iy = i >> 3, ix = i & 7;
    const int ysi = wy * 8 + iy, xsi = wx * 8 + ix;
    const int regi = (ysi >= 252 ? 2 : (ysi >= 248 ? 1 : 0)) * 3
                   + (xsi >= 252 ? 2 : (xsi >= 248 ? 1 : 0));
    float p[64]; float mx = -1e30f;
    #pragma unroll
    for (int j = 0; j < 64; ++j) {
        float s = 0.f;
        #pragma unroll
        for (int d2 = 0; d2 < 8; ++d2) {
            float2 kv = *(const float2*)&Wl[(h * 64 + j) * 18 + 2 * d2];  // broadcast
            s += qr[2 * d2] * kv.x + qr[2 * d2 + 1] * kv.y;
        }
        const int jy = j >> 3, jx = j & 7;
        s += rpbl[((iy - jy + 7) * 15 + (ix - jx + 7)) * 4 + h];
        const int ysj = wy * 8 + jy, xsj = wx * 8 + jx;
        const int regj = (ysj >= 252 ? 2 : (ysj >= 248 ? 1 : 0)) * 3
                       + (xsj >= 252 ? 2 : (xsj >= 248 ? 1 : 0));
        s += (regj == regi) ? 0.f : -100.f;
        p[j] = s; mx = fmaxf(mx, s);
    }
    float sum = 0.f;
    #pragma unroll
    for (int j = 0; j < 64; ++j) { float e = __expf(p[j] - mx); p[j] = e; sum += e; }
    const float inv = 1.f / sum;
    __syncthreads();   // Q,K dead for all waves

    // PV -> O tile (Xl pitch 68, token-major)
    float o[16];
    #pragma unroll
    for (int dd = 0; dd < 16; ++dd) o[dd] = 0.f;
    #pragma unroll
    for (int j = 0; j < 64; ++j) {
        const float pj = p[j] * inv;
        #pragma unroll
        for (int d2 = 0; d2 < 8; ++d2) {
            float2 vv = *(const float2*)&Wl[4608 + (h * 64 + j) * 18 + 2 * d2];  // broadcast
            o[2 * d2] += pj * vv.x; o[2 * d2 + 1] += pj * vv.y;
        }
    }
    #pragma unroll
    for (int dd = 0; dd < 16; ++dd) Xl[i * 68 + h * 16 + dd] = o[dd];
    __syncthreads();

    // proj GEMM
    for (int idx = tid; idx < 4096; idx += 256) Wl[idx] = projw[idx];
    __syncthreads();
    float pacc[16];
    #pragma unroll
    for (int j = 0; j < 16; ++j) pacc[j] = 0.f;
    for (int k4 = 0; k4 < 16; ++k4) {
        const float4 xv = *(const float4*)&Xl[t * 68 + 4 * k4];
        #pragma unroll
        for (int j = 0; j < 16; ++j) {
            const float4 wv = *(const float4*)&Wl[(mb + 4 * j) * 64 + 4 * k4];
            pacc[j] += xv.x * wv.x + xv.y * wv.y + xv.z * wv.z + xv.w * wv.w;
        }
    }
    #pragma unroll
    for (int j = 0; j < 16; ++j) {
        int oc = mb + 4 * j;
        Wl[4096 + t * 68 + oc] = pacc[j] + projb[oc];
    }
    __syncthreads();

    // Un-shift, add shortcut, write x3 (bf16 token-major)
    {
        const int chn = t, tl2 = mb;
        for (int it = 0; it < 16; ++it) {
            int tt = tl2 + 4 * it;
            int py = tt >> 3, px = tt & 7;
            int yo = (wy * 8 + py + 4) & 255, xo = (wx * 8 + px + 4) & 255;
            size_t tok = ((size_t)b << 16) + yo * 256 + xo;
            float sc = A[tok * 64 + chn];
            Cb[tok * 64 + chn] = __float2bfloat16(sc + Wl[4096 + tt * 68 + chn]);
        }
    }
}

// ---------------------------------------------------------------------------
// Kernel 3: LN2 + fc1 + GELU -> hidden image layout (b,256,h,w) fp8.
// ---------------------------------------------------------------------------
__global__ __launch_bounds__(256) void k_ln2fc1(const __hip_bfloat16* __restrict__ Cb,
        const float* __restrict__ w2, const float* __restrict__ b2,
        const float* __restrict__ fc1w, const float* __restrict__ fc1b,
        unsigned char* __restrict__ D) {
    __shared__ __align__(16) float Xt[64 * 68];
    __shared__ __align__(16) float Wc[4096];
    __shared__ float red0[256], red1[256], muv[64], rsv[64], lw[64], lb[64];
    const int tid = threadIdx.x, gid = blockIdx.x;
    const int xc = gid & 3, y = (gid >> 2) & 255, b = gid >> 10;
    const int x0 = xc * 64;
    if (tid < 64) { lw[tid] = w2[tid]; lb[tid] = b2[tid]; }
    const __hip_bfloat16* Cp = Cb + ((size_t)(b << 16) + y * 256 + x0) * 64;
    {
        const int ch = tid & 63, tl = tid >> 6;
        for (int it = 0; it < 16; ++it) {
            int tt = tl + 4 * it;
            Xt[tt * 68 + ch] = __bfloat162float(Cp[tt * 64 + ch]);
        }
    }
    __syncthreads();
    {
        const int tk = tid & 63, cl = tid >> 6;
        float s = 0.f, s2 = 0.f;
        #pragma unroll
        for (int k = 0; k < 4; ++k) {
            const float4 v = *(const float4*)&Xt[tk * 68 + cl * 16 + 4 * k];
            s  += v.x + v.y + v.z + v.w;
            s2 += v.x * v.x + v.y * v.y + v.z * v.z + v.w * v.w;
        }
        red0[cl * 64 + tk] = s; red1[cl * 64 + tk] = s2;
    }
    __syncthreads();
    if (tid < 64) {
        float s  = red0[tid] + red0[64 + tid] + red0[128 + tid] + red0[192 + tid];
        float s2 = red1[tid] + red1[64 + tid] + red1[128 + tid] + red1[192 + tid];
        float mu = s * (1.f / 64.f);
        float var = s2 * (1.f / 64.f) - mu * mu;
        muv[tid] = mu; rsv[tid] = rsqrtf(var + 1e-5f);
    }
    __syncthreads();
    {
        const int ch = tid & 63, tl = tid >> 6;
        for (int it = 0; it < 16; ++it) {
            int tt = tl + 4 * it;
            Xt[tt * 68 + ch] = (Xt[tt * 68 + ch] - muv[tt]) * rsv[tt] * lw[ch] + lb[ch];
        }
    }
    const int t = tid & 63, mbq = tid >> 6;
    for (int mc = 0; mc < 4; ++mc) {
        __syncthreads();
        for (int i = tid; i < 4096; i += 256) Wc[i] = fc1w[mc * 4096 + i];
        __syncthreads();
        float a16[16];
        #pragma unroll
        for (int j = 0; j < 16; ++j) a16[j] = 0.f;
        for (int k4 = 0; k4 < 16; ++k4) {
            const float4 xv = *(const float4*)&Xt[t * 68 + 4 * k4];
            #pragma unroll
            for (int j = 0; j < 16; ++j) {
                const float4 wv = *(const float4*)&Wc[(mbq + 4 * j) * 64 + 4 * k4];
                a16[j] += xv.x * wv.x + xv.y * wv.y + xv.z * wv.z + xv.w * wv.w;
            }
        }
        #pragma unroll
        for (int j = 0; j < 16; ++j) {
            int ml = mbq + 4 * j;
            float v = a16[j] + fc1b[mc * 64 + ml];
            D[((size_t)(b * 256 + mc * 64 + ml) << 16) + y * 256 + x0 + t] =
                f32_to_fp8(gelu_f(v));
        }
    }
}

// ---------------------------------------------------------------------------
// Kernel 4: depthwise 5x5 conv + GELU + residual add (image layout, fp8).
// ---------------------------------------------------------------------------
__global__ __launch_bounds__(256) void k_dwconv(const unsigned char* __restrict__ D,
        const float* __restrict__ dww, const float* __restrict__ dwb,
        unsigned char* __restrict__ E) {
    __shared__ float sm[20 * 68];
    const int tid = threadIdx.x, gid = blockIdx.x;
    const int xt = gid & 3, yt = (gid >> 2) & 15, pc = gid >> 6;
    const int ch = pc & 255;
    const int x0 = xt * 64, y0 = yt * 16;
    const unsigned char* Dp = D + ((size_t)pc << 16);
    for (int idx = tid; idx < 20 * 68; idx += 256) {
        int r = idx / 68, cc = idx - r * 68;
        int gy = y0 + r - 2, gx = x0 + cc - 2;
        float v = 0.f;
        if (gy >= 0 && gy < 256 && gx >= 0 && gx < 256)
            v = fp8_to_f32(Dp[gy * 256 + gx]);
        sm[idx] = v;
    }
    float wr[25];
    #pragma unroll
    for (int k = 0; k < 25; ++k) wr[k] = dww[ch * 25 + k];   // block-uniform
    const float bb = dwb[ch];
    __syncthreads();
    const int x = tid & 63, yl0 = tid >> 6;
    #pragma unroll
    for (int q = 0; q < 4; ++q) {
        const int yl = yl0 + 4 * q;
        float a = bb;
        #pragma unroll
        for (int ky = 0; ky < 5; ++ky)
            #pragma unroll
            for (int kx = 0; kx < 5; ++kx)
                a += wr[ky * 5 + kx] * sm[(yl + ky) * 68 + x + kx];
        const float g = gelu_f(a);
        const float cen = sm[(yl + 2) * 68 + x + 2];
        E[((size_t)pc << 16) + (y0 + yl) * 256 + x0 + x] = f32_to_fp8(cen + g);
    }
}

// ---------------------------------------------------------------------------
// Kernel 5: fc2 + bias + residual + transpose to (b,c,h,w) fp32 output.
// ---------------------------------------------------------------------------
__global__ __launch_bounds__(256) void k_fc2(const unsigned char* __restrict__ E,
        const __hip_bfloat16* __restrict__ Cb, const float* __restrict__ fc2w,
        const float* __restrict__ fc2b, float* __restrict__ out) {
    __shared__ __align__(16) float Cl[64 * 68];
    __shared__ __align__(16) float Hl[64 * 68];   // hid tile, later O tile
    __shared__ __align__(16) float W2[4096];
    const int tid = threadIdx.x, gid = blockIdx.x;
    const int xc = gid & 3, y = (gid >> 2) & 255, b = gid >> 10;
    const int x0 = xc * 64;
    const int t = tid & 63, qb = tid >> 6;
    {
        const __hip_bfloat16* Cp = Cb + ((size_t)(b << 16) + y * 256 + x0) * 64;
        const int ch = tid & 63, tl = tid >> 6;
        for (int it = 0; it < 16; ++it) {
            int tt = tl + 4 * it;
            Cl[tt * 68 + ch] = __bfloat162float(Cp[tt * 64 + ch]);
        }
    }
    float acc[16];
    #pragma unroll
    for (int j = 0; j < 16; ++j) acc[j] = 0.f;
    for (int mc = 0; mc < 4; ++mc) {
        __syncthreads();
        {   // hid chunk -> Hl[token][ml] pitch 68
            const unsigned char* Ep = E + ((size_t)(b * 256 + mc * 64) << 16)
                                        + y * 256 + x0;
            for (int it = 0; it < 16; ++it) {
                int ml = qb + 4 * it;
                Hl[t * 68 + ml] = fp8_to_f32(Ep[((size_t)ml << 16) + t]);
            }
        }
        {   // W2[oc][ml] chunk
            const int ml = t;
            for (int it = 0; it < 16; ++it) {
                int oc = qb + 4 * it;
                W2[oc * 64 + ml] = fc2w[oc * 256 + mc * 64 + ml];
            }
        }
        __syncthreads();
        for (int k4 = 0; k4 < 16; ++k4) {
            const float4 hv = *(const float4*)&Hl[t * 68 + 4 * k4];
            #pragma unroll
            for (int j = 0; j < 16; ++j) {
                const float4 wv = *(const float4*)&W2[(qb + 4 * j) * 64 + 4 * k4];
                acc[j] += hv.x * wv.x + hv.y * wv.y + hv.z * wv.z + hv.w * wv.w;
            }
        }
    }
    __syncthreads();
    #pragma unroll
    for (int j = 0; j < 16; ++j) {
        int oc = qb + 4 * j;
        Hl[oc * 68 + t] = acc[j] + fc2b[oc] + Cl[t * 68 + oc];   // O tile
    }
    __syncthreads();
    {
        for (int it = 0; it < 16; ++it) {
            int ch = qb + 4 * it;
            out[((size_t)(b * 64 + ch) << 16) + y * 256 + x0 + t] = Hl[ch * 68 + t];
        }
    }
}

// ---------------------------------------------------------------------------
extern "C" void kernel_launch(void* const* d_in, const int* in_sizes, int n_in,
                              void* d_out, int out_size, void* d_ws, size_t ws_size,
                              hipStream_t stream) {
    const float* x     = (const float*)d_in[0];
    const float* n1w   = (const float*)d_in[1];
    const float* n1b   = (const float*)d_in[2];
    const float* qkvw  = (const float*)d_in[3];
    const float* qkvb  = (const float*)d_in[4];
    const float* rpb   = (const float*)d_in[5];
    const float* projw = (const float*)d_in[6];
    const float* projb = (const float*)d_in[7];
    const float* n2w   = (const float*)d_in[8];
    const float* n2b   = (const float*)d_in[9];
    const float* fc1w  = (const float*)d_in[10];
    const float* fc1b  = (const float*)d_in[11];
    const float* dww   = (const float*)d_in[12];
    const float* dwb   = (const float*)d_in[13];
    const float* fc2w  = (const float*)d_in[14];
    const float* fc2b  = (const float*)d_in[15];
    float* out = (float*)d_out;

    char* ws = (char*)d_ws;
    const size_t MB = 1048576;
    __hip_bfloat16* Cbuf = (__hip_bfloat16*)ws;                 // [0,32M)
    float*          Ab   = (float*)(ws + 32 * MB);              // [32,96M)
    __hip_bfloat16* Bwp  = (__hip_bfloat16*)(ws + 96 * MB);     // [96,128M)
    unsigned char*  Dh   = (unsigned char*)(ws + 32 * MB);      // [32,96M)  alias A
    unsigned char*  Eh   = (unsigned char*)(ws + 96 * MB);      // [96,160M) alias Bw

    k_ln1   <<<4096,  256, 0, stream>>>(x, n1w, n1b, Ab, Bwp);
    k_attn  <<<4096,  256, 0, stream>>>(Bwp, qkvw, qkvb, rpb, projw, projb, Ab, Cbuf);
    k_ln2fc1<<<4096,  256, 0, stream>>>(Cbuf, n2w, n2b, fc1w, fc1b, Dh);
    k_dwconv<<<65536, 256, 0, stream>>>(Dh, dww, dwb, Eh);
    k_fc2   <<<4096,  256, 0, stream>>>(Eh, Cbuf, fc2w, fc2b, out);
}

// Round 3
// 923.667 us; speedup vs baseline: 1.4074x; 1.4074x over previous
//
#include <hip/hip_runtime.h>
#include <hip/hip_bf16.h>
#include <hip/hip_fp8.h>
#include <math.h>

// Problem constants: b=4, c=64, h=w=256, WS=8, SHIFT=4, HEADS=4, d=16, hidden=256
// Windows: 32x32 per image * 4 images = 4096; 64 tokens/window.
//
// Workspace layout (peak 160 MB):
//   Cb  bf16 32MB [0,32M)    x3 token-major        written k2, read k3+k5
//   A   bf16 32MB [32,64M)   shortcut token-major  written k1, read k2 (dead after)
//   Bw  bf16 32MB [64,96M)   shifted windows       written k1, read k2 (dead after)
//   D   fp8  64MB [32,96M)   hid image layout      written k3 (aliases A+Bw), read k4
//   E   fp8  64MB [96,160M)  hid+conv image layout written k4, read k5

typedef __bf16  bf16x8  __attribute__((ext_vector_type(8)));
typedef float   f32x4   __attribute__((ext_vector_type(4)));
typedef unsigned short ushortx8 __attribute__((ext_vector_type(8)));

__device__ __forceinline__ float gelu_f(float v) {
    return 0.5f * v * (1.0f + erff(v * 0.70710678118654752440f));
}
__device__ __forceinline__ unsigned char f32_to_fp8(float v) {
    __hip_fp8_e4m3 t(v);
    return (unsigned char)t.__x;
}
__device__ __forceinline__ float fp8_to_f32(unsigned char u) {
    __hip_fp8_e4m3 t;
    t.__x = (__hip_fp8_storage_t)u;
    return (float)t;
}
__device__ __forceinline__ unsigned short f2bf(float f) {   // RNE, matches HW
    unsigned int u = __builtin_bit_cast(unsigned int, f);
    u += 0x7fffu + ((u >> 16) & 1u);
    return (unsigned short)(u >> 16);
}
__device__ __forceinline__ float bf2f(unsigned short u) {
    return __builtin_bit_cast(float, ((unsigned int)u) << 16);
}

// ---------------------------------------------------------------------------
// Kernel 1: LN1 + transpose. Reads x (b,c,h,w). Writes:
//   A  : shortcut, token-major bf16 [b*65536 tokens][64 ch]
//   Bw : normalized, shifted+window-partitioned bf16 [4096 win][64 tok][64 ch]
// ---------------------------------------------------------------------------
__global__ __launch_bounds__(256) void k_ln1(const float* __restrict__ x,
        const float* __restrict__ w1, const float* __restrict__ b1,
        unsigned short* __restrict__ A, unsigned short* __restrict__ Bw) {
    __shared__ float tile[64 * 65];           // [ch][token]
    __shared__ float red0[256], red1[256];
    __shared__ float muv[64], rsv[64], lw[64], lb[64];
    const int tid = threadIdx.x;
    const int gid = blockIdx.x;
    const int xc = gid & 3, y = (gid >> 2) & 255, b = gid >> 10;
    const int x0 = xc * 64;
    if (tid < 64) { lw[tid] = w1[tid]; lb[tid] = b1[tid]; }

    const float* xb = x + ((size_t)b * 64) * 65536 + y * 256 + x0;
    {
        const int tk = tid & 63, cl = tid >> 6;
        for (int it = 0; it < 16; ++it) {
            int cc = cl + 4 * it;
            tile[cc * 65 + tk] = xb[(size_t)cc * 65536 + tk];   // coalesced
        }
    }
    __syncthreads();
    {
        const int tk = tid & 63, cl = tid >> 6;
        float s = 0.f, s2 = 0.f;
        #pragma unroll
        for (int k = 0; k < 16; ++k) {
            float v = tile[(cl * 16 + k) * 65 + tk];
            s += v; s2 += v * v;
        }
        red0[cl * 64 + tk] = s; red1[cl * 64 + tk] = s2;
    }
    __syncthreads();
    if (tid < 64) {
        float s  = red0[tid] + red0[64 + tid] + red0[128 + tid] + red0[192 + tid];
        float s2 = red1[tid] + red1[64 + tid] + red1[128 + tid] + red1[192 + tid];
        float mu = s * (1.f / 64.f);
        float var = s2 * (1.f / 64.f) - mu * mu;
        muv[tid] = mu; rsv[tid] = rsqrtf(var + 1e-5f);
    }
    __syncthreads();
    const int ch = tid & 63, tl = tid >> 6;
    const int ys = (y + 252) & 255;          // shifted row (roll -4)
    const int wy = ys >> 3, py = ys & 7;
    for (int it = 0; it < 16; ++it) {
        int t = tl + 4 * it;
        float v = tile[ch * 65 + t];         // stride 65 -> free 2-way
        int tok = (b << 16) + y * 256 + x0 + t;
        A[(size_t)tok * 64 + ch] = f2bf(v);
        float vn = (v - muv[t]) * rsv[t] * lw[ch] + lb[ch];
        int xs = (x0 + t + 252) & 255;
        int wx = xs >> 3, px = xs & 7;
        int widx = (b << 10) + (wy << 5) + wx;
        int pos = (py << 3) + px;
        Bw[((size_t)widx * 64 + pos) * 64 + ch] = f2bf(vn);
    }
}

// ---------------------------------------------------------------------------
// Kernel 2: windowed attention, MFMA bf16. One block per window, 4 waves.
// Wave w owns q-token m-tile [16w,16w+16). Q/P/O tiles are wave-private rows
// (only K and Vt are read cross-wave -> barriers only around those).
// LDS: Xq 9216B (X p72 -> Q p16 -> O p72) | WK 17408B (qkvw chunk p72 ->
//      K p16 [0,8K) + Vt p72 [8K,17.4K)) | Pb 9216B (P p72 -> projw p72)
// ---------------------------------------------------------------------------
__global__ __launch_bounds__(256) void k_attn(
        const unsigned short* __restrict__ Bw,
        const float* __restrict__ qkvw, const float* __restrict__ qkvb,
        const float* __restrict__ rpb,
        const float* __restrict__ projw, const float* __restrict__ projb,
        const unsigned short* __restrict__ A, unsigned short* __restrict__ Cb) {
    __shared__ __align__(16) unsigned short Xq[4608];
    __shared__ __align__(16) unsigned short WK[8704];
    __shared__ __align__(16) unsigned short Pb[4608];
    __shared__ unsigned short rpbl[900];
    __shared__ float qkvbl[192];
    __shared__ float projbl[64];

    const int tid = threadIdx.x;
    const int lane = tid & 63, wv = tid >> 6;
    const int l15 = lane & 15, quad = lane >> 4;
    const int widx = blockIdx.x;
    const int wib = widx & 1023;
    const int wy = wib >> 5, wx = wib & 31, bimg = widx >> 10;

    const f32x4 zz = {0.f, 0.f, 0.f, 0.f};
    const ushortx8 zu = {0, 0, 0, 0, 0, 0, 0, 0};
    const bf16x8 z8 = __builtin_bit_cast(bf16x8, zu);

    // ---- stage X window (pitch 72), rpb (bf16), biases ----
    {
        const unsigned short* Xg = Bw + (size_t)widx * 4096;
        #pragma unroll
        for (int i = 0; i < 16; ++i) {
            int idx = i * 256 + tid;
            Xq[(idx >> 6) * 72 + (idx & 63)] = Xg[idx];
        }
        for (int i = tid; i < 900; i += 256) rpbl[i] = f2bf(rpb[i]);
        if (tid < 192) qkvbl[tid] = qkvb[tid];
        if (tid < 64)  projbl[tid] = projb[tid];
    }
    __syncthreads();

    // ---- qkv GEMM: M=64 (wave m-tile), N=192 (2 chunks of 96), K=64 ----
    f32x4 qacc[12];
    #pragma unroll
    for (int i = 0; i < 12; ++i) qacc[i] = zz;
    for (int c = 0; c < 2; ++c) {
        if (c) __syncthreads();
        #pragma unroll
        for (int i = 0; i < 24; ++i) {      // 96 rows x 64 ch -> bf16 p72
            int idx = i * 256 + tid;
            WK[(idx >> 6) * 72 + (idx & 63)] = f2bf(qkvw[c * 6144 + idx]);
        }
        __syncthreads();
        #pragma unroll
        for (int gl = 0; gl < 6; ++gl)
            #pragma unroll
            for (int s = 0; s < 2; ++s) {
                bf16x8 av = *(const bf16x8*)&Xq[(16 * wv + l15) * 72 + s * 32 + quad * 8];
                bf16x8 bv = *(const bf16x8*)&WK[((gl << 4) + l15) * 72 + s * 32 + quad * 8];
                qacc[c * 6 + gl] =
                    __builtin_amdgcn_mfma_f32_16x16x32_bf16(av, bv, qacc[c * 6 + gl], 0, 0, 0);
            }
        __syncthreads();
    }

    // ---- scatter QKV: Q->Xq [h][tok][16] p16, K->WK p16, V^T->WK+4096 p72 ----
    #pragma unroll
    for (int g = 0; g < 12; ++g) {
        #pragma unroll
        for (int r = 0; r < 4; ++r) {
            int tok = 16 * wv + quad * 4 + r;       // C-layout row
            int oc  = g * 16 + l15;                 // C-layout col
            float v = qacc[g][r] + qkvbl[oc];
            if (g < 4)       Xq[g * 1024 + tok * 16 + l15] = f2bf(v * 0.25f);
            else if (g < 8)  WK[(g - 4) * 1024 + tok * 16 + l15] = f2bf(v);
            else             WK[4096 + ((g - 8) * 16 + l15) * 72 + tok] = f2bf(v);
        }
    }
    __syncthreads();

    // ---- scores: per head, 16x16x32 MFMA with K=16 (quad>=2 frags zero) ----
    f32x4 sacc[4][4];
    #pragma unroll
    for (int h = 0; h < 4; ++h) {
        bf16x8 qa = z8;
        if (quad < 2) qa = *(const bf16x8*)&Xq[h * 1024 + (16 * wv + l15) * 16 + quad * 8];
        #pragma unroll
        for (int nt = 0; nt < 4; ++nt) {
            bf16x8 kf = z8;
            if (quad < 2) kf = *(const bf16x8*)&WK[h * 1024 + (nt * 16 + l15) * 16 + quad * 8];
            sacc[h][nt] = __builtin_amdgcn_mfma_f32_16x16x32_bf16(qa, kf, zz, 0, 0, 0);
        }
    }

    // ---- per head: bias+mask+softmax (regs) -> P (own rows) -> PV ----
    f32x4 o[4];
    #pragma unroll
    for (int h = 0; h < 4; ++h) {
        #pragma unroll
        for (int r = 0; r < 4; ++r) {
            const int i  = 16 * wv + quad * 4 + r;
            const int iy = i >> 3, ix = i & 7;
            const int ysi = wy * 8 + iy, xsi = wx * 8 + ix;
            const int regi = (ysi >= 252 ? 2 : (ysi >= 248 ? 1 : 0)) * 3
                           + (xsi >= 252 ? 2 : (xsi >= 248 ? 1 : 0));
            float m0 = -1e30f;
            #pragma unroll
            for (int nt = 0; nt < 4; ++nt) {
                const int j = nt * 16 + l15;
                const int jy = j >> 3, jx = j & 7;
                float s = sacc[h][nt][r]
                        + bf2f(rpbl[((iy - jy + 7) * 15 + (ix - jx + 7)) * 4 + h]);
                const int ysj = wy * 8 + jy, xsj = wx * 8 + jx;
                const int regj = (ysj >= 252 ? 2 : (ysj >= 248 ? 1 : 0)) * 3
                               + (xsj >= 252 ? 2 : (xsj >= 248 ? 1 : 0));
                s += (regj == regi) ? 0.f : -100.f;
                sacc[h][nt][r] = s;
                m0 = fmaxf(m0, s);
            }
            m0 = fmaxf(m0, __shfl_xor(m0, 1));
            m0 = fmaxf(m0, __shfl_xor(m0, 2));
            m0 = fmaxf(m0, __shfl_xor(m0, 4));
            m0 = fmaxf(m0, __shfl_xor(m0, 8));
            float s0 = 0.f;
            #pragma unroll
            for (int nt = 0; nt < 4; ++nt) {
                float e = __expf(sacc[h][nt][r] - m0);
                sacc[h][nt][r] = e; s0 += e;
            }
            s0 += __shfl_xor(s0, 1); s0 += __shfl_xor(s0, 2);
            s0 += __shfl_xor(s0, 4); s0 += __shfl_xor(s0, 8);
            const float inv = 1.f / s0;
            #pragma unroll
            for (int nt = 0; nt < 4; ++nt)
                Pb[i * 72 + nt * 16 + l15] = f2bf(sacc[h][nt][r] * inv);
        }
        // PV: rows are wave-private -> no barrier (lgkmcnt only)
        o[h] = zz;
        #pragma unroll
        for (int s = 0; s < 2; ++s) {
            bf16x8 pa = *(const bf16x8*)&Pb[(16 * wv + l15) * 72 + s * 32 + quad * 8];
            bf16x8 vb = *(const bf16x8*)&WK[4096 + (h * 16 + l15) * 72 + s * 32 + quad * 8];
            o[h] = __builtin_amdgcn_mfma_f32_16x16x32_bf16(pa, vb, o[h], 0, 0, 0);
        }
    }
    __syncthreads();     // all Q reads done before O overwrites Xq region

    // ---- O tile -> Xq (p72, token-major) ----
    #pragma unroll
    for (int h = 0; h < 4; ++h)
        #pragma unroll
        for (int r = 0; r < 4; ++r)
            Xq[(16 * wv + quad * 4 + r) * 72 + h * 16 + l15] = f2bf(o[h][r]);
    __syncthreads();

    // ---- proj GEMM: stage projw into Pb (p72), M=64,N=64,K=64 ----
    #pragma unroll
    for (int i = 0; i < 16; ++i) {
        int idx = i * 256 + tid;
        Pb[(idx >> 6) * 72 + (idx & 63)] = f2bf(projw[idx]);
    }
    __syncthreads();
    f32x4 pacc[4];
    #pragma unroll
    for (int nt = 0; nt < 4; ++nt) {
        pacc[nt] = zz;
        #pragma unroll
        for (int s = 0; s < 2; ++s) {
            bf16x8 oa = *(const bf16x8*)&Xq[(16 * wv + l15) * 72 + s * 32 + quad * 8];
            bf16x8 wb = *(const bf16x8*)&Pb[(nt * 16 + l15) * 72 + s * 32 + quad * 8];
            pacc[nt] = __builtin_amdgcn_mfma_f32_16x16x32_bf16(oa, wb, pacc[nt], 0, 0, 0);
        }
    }

    // ---- epilogue: +projb, +shortcut, un-shift, write Cb bf16 ----
    #pragma unroll
    for (int nt = 0; nt < 4; ++nt)
        #pragma unroll
        for (int r = 0; r < 4; ++r) {
            const int tok = 16 * wv + quad * 4 + r;
            const int oc  = nt * 16 + l15;
            const int py = tok >> 3, px = tok & 7;
            const int yo = (wy * 8 + py + 4) & 255, xo = (wx * 8 + px + 4) & 255;
            const size_t gt = ((size_t)bimg << 16) + yo * 256 + xo;
            float v = pacc[nt][r] + projbl[oc] + bf2f(A[gt * 64 + oc]);
            Cb[gt * 64 + oc] = f2bf(v);
        }
}

// ---------------------------------------------------------------------------
// Kernel 3: LN2 + fc1 + GELU -> hidden image layout (b,256,h,w) fp8.
// ---------------------------------------------------------------------------
__global__ __launch_bounds__(256) void k_ln2fc1(const __hip_bfloat16* __restrict__ Cb,
        const float* __restrict__ w2, const float* __restrict__ b2,
        const float* __restrict__ fc1w, const float* __restrict__ fc1b,
        unsigned char* __restrict__ D) {
    __shared__ __align__(16) float Xt[64 * 68];
    __shared__ __align__(16) float Wc[4096];
    __shared__ float red0[256], red1[256], muv[64], rsv[64], lw[64], lb[64];
    const int tid = threadIdx.x, gid = blockIdx.x;
    const int xc = gid & 3, y = (gid >> 2) & 255, b = gid >> 10;
    const int x0 = xc * 64;
    if (tid < 64) { lw[tid] = w2[tid]; lb[tid] = b2[tid]; }
    const __hip_bfloat16* Cp = Cb + ((size_t)(b << 16) + y * 256 + x0) * 64;
    {
        const int ch = tid & 63, tl = tid >> 6;
        for (int it = 0; it < 16; ++it) {
            int tt = tl + 4 * it;
            Xt[tt * 68 + ch] = __bfloat162float(Cp[tt * 64 + ch]);
        }
    }
    __syncthreads();
    {
        const int tk = tid & 63, cl = tid >> 6;
        float s = 0.f, s2 = 0.f;
        #pragma unroll
        for (int k = 0; k < 4; ++k) {
            const float4 v = *(const float4*)&Xt[tk * 68 + cl * 16 + 4 * k];
            s  += v.x + v.y + v.z + v.w;
            s2 += v.x * v.x + v.y * v.y + v.z * v.z + v.w * v.w;
        }
        red0[cl * 64 + tk] = s; red1[cl * 64 + tk] = s2;
    }
    __syncthreads();
    if (tid < 64) {
        float s  = red0[tid] + red0[64 + tid] + red0[128 + tid] + red0[192 + tid];
        float s2 = red1[tid] + red1[64 + tid] + red1[128 + tid] + red1[192 + tid];
        float mu = s * (1.f / 64.f);
        float var = s2 * (1.f / 64.f) - mu * mu;
        muv[tid] = mu; rsv[tid] = rsqrtf(var + 1e-5f);
    }
    __syncthreads();
    {
        const int ch = tid & 63, tl = tid >> 6;
        for (int it = 0; it < 16; ++it) {
            int tt = tl + 4 * it;
            Xt[tt * 68 + ch] = (Xt[tt * 68 + ch] - muv[tt]) * rsv[tt] * lw[ch] + lb[ch];
        }
    }
    const int t = tid & 63, mbq = tid >> 6;
    for (int mc = 0; mc < 4; ++mc) {
        __syncthreads();
        for (int i = tid; i < 4096; i += 256) Wc[i] = fc1w[mc * 4096 + i];
        __syncthreads();
        float a16[16];
        #pragma unroll
        for (int j = 0; j < 16; ++j) a16[j] = 0.f;
        for (int k4 = 0; k4 < 16; ++k4) {
            const float4 xv = *(const float4*)&Xt[t * 68 + 4 * k4];
            #pragma unroll
            for (int j = 0; j < 16; ++j) {
                const float4 wv = *(const float4*)&Wc[(mbq + 4 * j) * 64 + 4 * k4];
                a16[j] += xv.x * wv.x + xv.y * wv.y + xv.z * wv.z + xv.w * wv.w;
            }
        }
        #pragma unroll
        for (int j = 0; j < 16; ++j) {
            int ml = mbq + 4 * j;
            float v = a16[j] + fc1b[mc * 64 + ml];
            D[((size_t)(b * 256 + mc * 64 + ml) << 16) + y * 256 + x0 + t] =
                f32_to_fp8(gelu_f(v));
        }
    }
}

// ---------------------------------------------------------------------------
// Kernel 4: depthwise 5x5 conv + GELU + residual add (image layout, fp8).
// ---------------------------------------------------------------------------
__global__ __launch_bounds__(256) void k_dwconv(const unsigned char* __restrict__ D,
        const float* __restrict__ dww, const float* __restrict__ dwb,
        unsigned char* __restrict__ E) {
    __shared__ float sm[20 * 68];
    const int tid = threadIdx.x, gid = blockIdx.x;
    const int xt = gid & 3, yt = (gid >> 2) & 15, pc = gid >> 6;
    const int ch = pc & 255;
    const int x0 = xt * 64, y0 = yt * 16;
    const unsigned char* Dp = D + ((size_t)pc << 16);
    for (int idx = tid; idx < 20 * 68; idx += 256) {
        int r = idx / 68, cc = idx - r * 68;
        int gy = y0 + r - 2, gx = x0 + cc - 2;
        float v = 0.f;
        if (gy >= 0 && gy < 256 && gx >= 0 && gx < 256)
            v = fp8_to_f32(Dp[gy * 256 + gx]);
        sm[idx] = v;
    }
    float wr[25];
    #pragma unroll
    for (int k = 0; k < 25; ++k) wr[k] = dww[ch * 25 + k];   // block-uniform
    const float bb = dwb[ch];
    __syncthreads();
    const int x = tid & 63, yl0 = tid >> 6;
    #pragma unroll
    for (int q = 0; q < 4; ++q) {
        const int yl = yl0 + 4 * q;
        float a = bb;
        #pragma unroll
        for (int ky = 0; ky < 5; ++ky)
            #pragma unroll
            for (int kx = 0; kx < 5; ++kx)
                a += wr[ky * 5 + kx] * sm[(yl + ky) * 68 + x + kx];
        const float g = gelu_f(a);
        const float cen = sm[(yl + 2) * 68 + x + 2];
        E[((size_t)pc << 16) + (y0 + yl) * 256 + x0 + x] = f32_to_fp8(cen + g);
    }
}

// ---------------------------------------------------------------------------
// Kernel 5: fc2 + bias + residual + transpose to (b,c,h,w) fp32 output.
// ---------------------------------------------------------------------------
__global__ __launch_bounds__(256) void k_fc2(const unsigned char* __restrict__ E,
        const __hip_bfloat16* __restrict__ Cb, const float* __restrict__ fc2w,
        const float* __restrict__ fc2b, float* __restrict__ out) {
    __shared__ __align__(16) float Cl[64 * 68];
    __shared__ __align__(16) float Hl[64 * 68];   // hid tile, later O tile
    __shared__ __align__(16) float W2[4096];
    const int tid = threadIdx.x, gid = blockIdx.x;
    const int xc = gid & 3, y = (gid >> 2) & 255, b = gid >> 10;
    const int x0 = xc * 64;
    const int t = tid & 63, qb = tid >> 6;
    {
        const __hip_bfloat16* Cp = Cb + ((size_t)(b << 16) + y * 256 + x0) * 64;
        const int ch = tid & 63, tl = tid >> 6;
        for (int it = 0; it < 16; ++it) {
            int tt = tl + 4 * it;
            Cl[tt * 68 + ch] = __bfloat162float(Cp[tt * 64 + ch]);
        }
    }
    float acc[16];
    #pragma unroll
    for (int j = 0; j < 16; ++j) acc[j] = 0.f;
    for (int mc = 0; mc < 4; ++mc) {
        __syncthreads();
        {   // hid chunk -> Hl[token][ml] pitch 68
            const unsigned char* Ep = E + ((size_t)(b * 256 + mc * 64) << 16)
                                        + y * 256 + x0;
            for (int it = 0; it < 16; ++it) {
                int ml = qb + 4 * it;
                Hl[t * 68 + ml] = fp8_to_f32(Ep[((size_t)ml << 16) + t]);
            }
        }
        {   // W2[oc][ml] chunk
            const int ml = t;
            for (int it = 0; it < 16; ++it) {
                int oc = qb + 4 * it;
                W2[oc * 64 + ml] = fc2w[oc * 256 + mc * 64 + ml];
            }
        }
        __syncthreads();
        for (int k4 = 0; k4 < 16; ++k4) {
            const float4 hv = *(const float4*)&Hl[t * 68 + 4 * k4];
            #pragma unroll
            for (int j = 0; j < 16; ++j) {
                const float4 wv = *(const float4*)&W2[(qb + 4 * j) * 64 + 4 * k4];
                acc[j] += hv.x * wv.x + hv.y * wv.y + hv.z * wv.z + hv.w * wv.w;
            }
        }
    }
    __syncthreads();
    #pragma unroll
    for (int j = 0; j < 16; ++j) {
        int oc = qb + 4 * j;
        Hl[oc * 68 + t] = acc[j] + fc2b[oc] + Cl[t * 68 + oc];   // O tile
    }
    __syncthreads();
    {
        for (int it = 0; it < 16; ++it) {
            int ch = qb + 4 * it;
            out[((size_t)(b * 64 + ch) << 16) + y * 256 + x0 + t] = Hl[ch * 68 + t];
        }
    }
}

// ---------------------------------------------------------------------------
extern "C" void kernel_launch(void* const* d_in, const int* in_sizes, int n_in,
                              void* d_out, int out_size, void* d_ws, size_t ws_size,
                              hipStream_t stream) {
    const float* x     = (const float*)d_in[0];
    const float* n1w   = (const float*)d_in[1];
    const float* n1b   = (const float*)d_in[2];
    const float* qkvw  = (const float*)d_in[3];
    const float* qkvb  = (const float*)d_in[4];
    const float* rpb   = (const float*)d_in[5];
    const float* projw = (const float*)d_in[6];
    const float* projb = (const float*)d_in[7];
    const float* n2w   = (const float*)d_in[8];
    const float* n2b   = (const float*)d_in[9];
    const float* fc1w  = (const float*)d_in[10];
    const float* fc1b  = (const float*)d_in[11];
    const float* dww   = (const float*)d_in[12];
    const float* dwb   = (const float*)d_in[13];
    const float* fc2w  = (const float*)d_in[14];
    const float* fc2b  = (const float*)d_in[15];
    float* out = (float*)d_out;

    char* ws = (char*)d_ws;
    const size_t MB = 1048576;
    unsigned short* Cbuf = (unsigned short*)ws;                  // [0,32M)
    unsigned short* Ab   = (unsigned short*)(ws + 32 * MB);      // [32,64M)
    unsigned short* Bwp  = (unsigned short*)(ws + 64 * MB);      // [64,96M)
    unsigned char*  Dh   = (unsigned char*)(ws + 32 * MB);       // [32,96M)  alias A+Bw
    unsigned char*  Eh   = (unsigned char*)(ws + 96 * MB);       // [96,160M)

    k_ln1   <<<4096,  256, 0, stream>>>(x, n1w, n1b, Ab, Bwp);
    k_attn  <<<4096,  256, 0, stream>>>(Bwp, qkvw, qkvb, rpb, projw, projb, Ab, Cbuf);
    k_ln2fc1<<<4096,  256, 0, stream>>>((const __hip_bfloat16*)Cbuf, n2w, n2b, fc1w, fc1b, Dh);
    k_dwconv<<<65536, 256, 0, stream>>>(Dh, dww, dwb, Eh);
    k_fc2   <<<4096,  256, 0, stream>>>(Eh, (const __hip_bfloat16*)Cbuf, fc2w, fc2b, out);
}

// Round 4
// 597.068 us; speedup vs baseline: 2.1773x; 1.5470x over previous
//
#include <hip/hip_runtime.h>
#include <hip/hip_bf16.h>
#include <hip/hip_fp8.h>
#include <math.h>

// Problem constants: b=4, c=64, h=w=256, WS=8, SHIFT=4, HEADS=4, d=16, hidden=256
// Windows: 32x32 per image * 4 images = 4096; 64 tokens/window.
//
// Workspace layout (peak 160 MB):
//   Cb  bf16 32MB [0,32M)    x3 token-major        written k2, read k3+k5
//   A   bf16 32MB [32,64M)   shortcut token-major  written k1, read k2 (dead after)
//   Bw  bf16 32MB [64,96M)   shifted windows       written k1, read k2 (dead after)
//   D   fp8  64MB [32,96M)   hid image layout      written k3 (aliases A+Bw), read k4
//   E   fp8  64MB [96,160M)  hid+conv image layout written k4, read k5

typedef __bf16  bf16x8  __attribute__((ext_vector_type(8)));
typedef float   f32x4   __attribute__((ext_vector_type(4)));
typedef unsigned short ushortx8 __attribute__((ext_vector_type(8)));

__device__ __forceinline__ float gelu_f(float v) {
    return 0.5f * v * (1.0f + erff(v * 0.70710678118654752440f));
}
__device__ __forceinline__ unsigned char f32_to_fp8(float v) {
    __hip_fp8_e4m3 t(v);
    return (unsigned char)t.__x;
}
__device__ __forceinline__ float fp8_to_f32(unsigned char u) {
    __hip_fp8_e4m3 t;
    t.__x = (__hip_fp8_storage_t)u;
    return (float)t;
}
__device__ __forceinline__ unsigned short f2bf(float f) {   // RNE, matches HW
    unsigned int u = __builtin_bit_cast(unsigned int, f);
    u += 0x7fffu + ((u >> 16) & 1u);
    return (unsigned short)(u >> 16);
}
__device__ __forceinline__ float bf2f(unsigned short u) {
    return __builtin_bit_cast(float, ((unsigned int)u) << 16);
}

// ---------------------------------------------------------------------------
// Kernel 1: LN1 + transpose. Reads x (b,c,h,w). Writes:
//   A  : shortcut, token-major bf16 [b*65536 tokens][64 ch]
//   Bw : normalized, shifted+window-partitioned bf16 [4096 win][64 tok][64 ch]
// ---------------------------------------------------------------------------
__global__ __launch_bounds__(256) void k_ln1(const float* __restrict__ x,
        const float* __restrict__ w1, const float* __restrict__ b1,
        unsigned short* __restrict__ A, unsigned short* __restrict__ Bw) {
    __shared__ float tile[64 * 65];           // [ch][token]
    __shared__ float red0[256], red1[256];
    __shared__ float muv[64], rsv[64], lw[64], lb[64];
    const int tid = threadIdx.x;
    const int gid = blockIdx.x;
    const int xc = gid & 3, y = (gid >> 2) & 255, b = gid >> 10;
    const int x0 = xc * 64;
    if (tid < 64) { lw[tid] = w1[tid]; lb[tid] = b1[tid]; }

    const float* xb = x + ((size_t)b * 64) * 65536 + y * 256 + x0;
    {
        const int tk = tid & 63, cl = tid >> 6;
        for (int it = 0; it < 16; ++it) {
            int cc = cl + 4 * it;
            tile[cc * 65 + tk] = xb[(size_t)cc * 65536 + tk];   // coalesced
        }
    }
    __syncthreads();
    {
        const int tk = tid & 63, cl = tid >> 6;
        float s = 0.f, s2 = 0.f;
        #pragma unroll
        for (int k = 0; k < 16; ++k) {
            float v = tile[(cl * 16 + k) * 65 + tk];
            s += v; s2 += v * v;
        }
        red0[cl * 64 + tk] = s; red1[cl * 64 + tk] = s2;
    }
    __syncthreads();
    if (tid < 64) {
        float s  = red0[tid] + red0[64 + tid] + red0[128 + tid] + red0[192 + tid];
        float s2 = red1[tid] + red1[64 + tid] + red1[128 + tid] + red1[192 + tid];
        float mu = s * (1.f / 64.f);
        float var = s2 * (1.f / 64.f) - mu * mu;
        muv[tid] = mu; rsv[tid] = rsqrtf(var + 1e-5f);
    }
    __syncthreads();
    const int ch = tid & 63, tl = tid >> 6;
    const int ys = (y + 252) & 255;          // shifted row (roll -4)
    const int wy = ys >> 3, py = ys & 7;
    for (int it = 0; it < 16; ++it) {
        int t = tl + 4 * it;
        float v = tile[ch * 65 + t];         // stride 65 -> free 2-way
        int tok = (b << 16) + y * 256 + x0 + t;
        A[(size_t)tok * 64 + ch] = f2bf(v);
        float vn = (v - muv[t]) * rsv[t] * lw[ch] + lb[ch];
        int xs = (x0 + t + 252) & 255;
        int wx = xs >> 3, px = xs & 7;
        int widx = (b << 10) + (wy << 5) + wx;
        int pos = (py << 3) + px;
        Bw[((size_t)widx * 64 + pos) * 64 + ch] = f2bf(vn);
    }
}

// ---------------------------------------------------------------------------
// Kernel 2: windowed attention, MFMA bf16 (unchanged from R3).
// ---------------------------------------------------------------------------
__global__ __launch_bounds__(256) void k_attn(
        const unsigned short* __restrict__ Bw,
        const float* __restrict__ qkvw, const float* __restrict__ qkvb,
        const float* __restrict__ rpb,
        const float* __restrict__ projw, const float* __restrict__ projb,
        const unsigned short* __restrict__ A, unsigned short* __restrict__ Cb) {
    __shared__ __align__(16) unsigned short Xq[4608];
    __shared__ __align__(16) unsigned short WK[8704];
    __shared__ __align__(16) unsigned short Pb[4608];
    __shared__ unsigned short rpbl[900];
    __shared__ float qkvbl[192];
    __shared__ float projbl[64];

    const int tid = threadIdx.x;
    const int lane = tid & 63, wv = tid >> 6;
    const int l15 = lane & 15, quad = lane >> 4;
    const int widx = blockIdx.x;
    const int wib = widx & 1023;
    const int wy = wib >> 5, wx = wib & 31, bimg = widx >> 10;

    const f32x4 zz = {0.f, 0.f, 0.f, 0.f};
    const ushortx8 zu = {0, 0, 0, 0, 0, 0, 0, 0};
    const bf16x8 z8 = __builtin_bit_cast(bf16x8, zu);

    {
        const unsigned short* Xg = Bw + (size_t)widx * 4096;
        #pragma unroll
        for (int i = 0; i < 16; ++i) {
            int idx = i * 256 + tid;
            Xq[(idx >> 6) * 72 + (idx & 63)] = Xg[idx];
        }
        for (int i = tid; i < 900; i += 256) rpbl[i] = f2bf(rpb[i]);
        if (tid < 192) qkvbl[tid] = qkvb[tid];
        if (tid < 64)  projbl[tid] = projb[tid];
    }
    __syncthreads();

    f32x4 qacc[12];
    #pragma unroll
    for (int i = 0; i < 12; ++i) qacc[i] = zz;
    for (int c = 0; c < 2; ++c) {
        if (c) __syncthreads();
        #pragma unroll
        for (int i = 0; i < 24; ++i) {
            int idx = i * 256 + tid;
            WK[(idx >> 6) * 72 + (idx & 63)] = f2bf(qkvw[c * 6144 + idx]);
        }
        __syncthreads();
        #pragma unroll
        for (int gl = 0; gl < 6; ++gl)
            #pragma unroll
            for (int s = 0; s < 2; ++s) {
                bf16x8 av = *(const bf16x8*)&Xq[(16 * wv + l15) * 72 + s * 32 + quad * 8];
                bf16x8 bv = *(const bf16x8*)&WK[((gl << 4) + l15) * 72 + s * 32 + quad * 8];
                qacc[c * 6 + gl] =
                    __builtin_amdgcn_mfma_f32_16x16x32_bf16(av, bv, qacc[c * 6 + gl], 0, 0, 0);
            }
        __syncthreads();
    }

    #pragma unroll
    for (int g = 0; g < 12; ++g) {
        #pragma unroll
        for (int r = 0; r < 4; ++r) {
            int tok = 16 * wv + quad * 4 + r;
            int oc  = g * 16 + l15;
            float v = qacc[g][r] + qkvbl[oc];
            if (g < 4)       Xq[g * 1024 + tok * 16 + l15] = f2bf(v * 0.25f);
            else if (g < 8)  WK[(g - 4) * 1024 + tok * 16 + l15] = f2bf(v);
            else             WK[4096 + ((g - 8) * 16 + l15) * 72 + tok] = f2bf(v);
        }
    }
    __syncthreads();

    f32x4 sacc[4][4];
    #pragma unroll
    for (int h = 0; h < 4; ++h) {
        bf16x8 qa = z8;
        if (quad < 2) qa = *(const bf16x8*)&Xq[h * 1024 + (16 * wv + l15) * 16 + quad * 8];
        #pragma unroll
        for (int nt = 0; nt < 4; ++nt) {
            bf16x8 kf = z8;
            if (quad < 2) kf = *(const bf16x8*)&WK[h * 1024 + (nt * 16 + l15) * 16 + quad * 8];
            sacc[h][nt] = __builtin_amdgcn_mfma_f32_16x16x32_bf16(qa, kf, zz, 0, 0, 0);
        }
    }

    f32x4 o[4];
    #pragma unroll
    for (int h = 0; h < 4; ++h) {
        #pragma unroll
        for (int r = 0; r < 4; ++r) {
            const int i  = 16 * wv + quad * 4 + r;
            const int iy = i >> 3, ix = i & 7;
            const int ysi = wy * 8 + iy, xsi = wx * 8 + ix;
            const int regi = (ysi >= 252 ? 2 : (ysi >= 248 ? 1 : 0)) * 3
                           + (xsi >= 252 ? 2 : (xsi >= 248 ? 1 : 0));
            float m0 = -1e30f;
            #pragma unroll
            for (int nt = 0; nt < 4; ++nt) {
                const int j = nt * 16 + l15;
                const int jy = j >> 3, jx = j & 7;
                float s = sacc[h][nt][r]
                        + bf2f(rpbl[((iy - jy + 7) * 15 + (ix - jx + 7)) * 4 + h]);
                const int ysj = wy * 8 + jy, xsj = wx * 8 + jx;
                const int regj = (ysj >= 252 ? 2 : (ysj >= 248 ? 1 : 0)) * 3
                               + (xsj >= 252 ? 2 : (xsj >= 248 ? 1 : 0));
                s += (regj == regi) ? 0.f : -100.f;
                sacc[h][nt][r] = s;
                m0 = fmaxf(m0, s);
            }
            m0 = fmaxf(m0, __shfl_xor(m0, 1));
            m0 = fmaxf(m0, __shfl_xor(m0, 2));
            m0 = fmaxf(m0, __shfl_xor(m0, 4));
            m0 = fmaxf(m0, __shfl_xor(m0, 8));
            float s0 = 0.f;
            #pragma unroll
            for (int nt = 0; nt < 4; ++nt) {
                float e = __expf(sacc[h][nt][r] - m0);
                sacc[h][nt][r] = e; s0 += e;
            }
            s0 += __shfl_xor(s0, 1); s0 += __shfl_xor(s0, 2);
            s0 += __shfl_xor(s0, 4); s0 += __shfl_xor(s0, 8);
            const float inv = 1.f / s0;
            #pragma unroll
            for (int nt = 0; nt < 4; ++nt)
                Pb[i * 72 + nt * 16 + l15] = f2bf(sacc[h][nt][r] * inv);
        }
        o[h] = zz;
        #pragma unroll
        for (int s = 0; s < 2; ++s) {
            bf16x8 pa = *(const bf16x8*)&Pb[(16 * wv + l15) * 72 + s * 32 + quad * 8];
            bf16x8 vb = *(const bf16x8*)&WK[4096 + (h * 16 + l15) * 72 + s * 32 + quad * 8];
            o[h] = __builtin_amdgcn_mfma_f32_16x16x32_bf16(pa, vb, o[h], 0, 0, 0);
        }
    }
    __syncthreads();

    #pragma unroll
    for (int h = 0; h < 4; ++h)
        #pragma unroll
        for (int r = 0; r < 4; ++r)
            Xq[(16 * wv + quad * 4 + r) * 72 + h * 16 + l15] = f2bf(o[h][r]);
    __syncthreads();

    #pragma unroll
    for (int i = 0; i < 16; ++i) {
        int idx = i * 256 + tid;
        Pb[(idx >> 6) * 72 + (idx & 63)] = f2bf(projw[idx]);
    }
    __syncthreads();
    f32x4 pacc[4];
    #pragma unroll
    for (int nt = 0; nt < 4; ++nt) {
        pacc[nt] = zz;
        #pragma unroll
        for (int s = 0; s < 2; ++s) {
            bf16x8 oa = *(const bf16x8*)&Xq[(16 * wv + l15) * 72 + s * 32 + quad * 8];
            bf16x8 wb = *(const bf16x8*)&Pb[(nt * 16 + l15) * 72 + s * 32 + quad * 8];
            pacc[nt] = __builtin_amdgcn_mfma_f32_16x16x32_bf16(oa, wb, pacc[nt], 0, 0, 0);
        }
    }

    #pragma unroll
    for (int nt = 0; nt < 4; ++nt)
        #pragma unroll
        for (int r = 0; r < 4; ++r) {
            const int tok = 16 * wv + quad * 4 + r;
            const int oc  = nt * 16 + l15;
            const int py = tok >> 3, px = tok & 7;
            const int yo = (wy * 8 + py + 4) & 255, xo = (wx * 8 + px + 4) & 255;
            const size_t gt = ((size_t)bimg << 16) + yo * 256 + xo;
            float v = pacc[nt][r] + projbl[oc] + bf2f(A[gt * 64 + oc]);
            Cb[gt * 64 + oc] = f2bf(v);
        }
}

// ---------------------------------------------------------------------------
// Kernel 3: LN2 + fc1 + GELU -> D (image layout fp8), MFMA bf16.
// A = fc1w (m = hidden ch 256), B = LN(x) (n = 64 tokens) => C col = token:
// direct coalesced fp8 stores, no epilogue transpose. Wave wv owns hidden
// chs [64wv, 64wv+64).
// ---------------------------------------------------------------------------
__global__ __launch_bounds__(256) void k_ln2fc1(const unsigned short* __restrict__ Cb,
        const float* __restrict__ w2, const float* __restrict__ b2,
        const float* __restrict__ fc1w, const float* __restrict__ fc1b,
        unsigned char* __restrict__ D) {
    __shared__ __align__(16) unsigned short Xb[64 * 72];    // raw->normalized bf16
    __shared__ __align__(16) unsigned short Wb[256 * 72];   // fc1w bf16
    __shared__ float red0[256], red1[256];
    __shared__ float muv[64], rsv[64], lwv[64], lbv[64], fb[256];
    const int tid = threadIdx.x, gid = blockIdx.x;
    const int xc = gid & 3, y = (gid >> 2) & 255, b = gid >> 10;
    const int x0 = xc * 64;
    const int lane = tid & 63, wv = tid >> 6;
    const int l15 = lane & 15, quad = lane >> 4;
    const f32x4 zz = {0.f, 0.f, 0.f, 0.f};

    if (tid < 64) { lwv[tid] = w2[tid]; lbv[tid] = b2[tid]; }
    fb[tid] = fc1b[tid];

    // stage Cb -> Xb (raw bf16, coalesced)
    const unsigned short* Cp = Cb + ((size_t)(b << 16) + y * 256 + x0) * 64;
    #pragma unroll
    for (int it = 0; it < 16; ++it) {
        int tt = wv + 4 * it;
        Xb[tt * 72 + lane] = Cp[tt * 64 + lane];
    }
    // stage fc1w -> Wb bf16 (overlaps with LN phases' latency)
    {
        const float4* w4 = (const float4*)fc1w;
        #pragma unroll
        for (int it = 0; it < 16; ++it) {
            int idx4 = it * 256 + tid;
            float4 v = w4[idx4];
            int row = idx4 >> 4, c4 = idx4 & 15;
            unsigned short* p = &Wb[row * 72 + c4 * 4];
            p[0] = f2bf(v.x); p[1] = f2bf(v.y); p[2] = f2bf(v.z); p[3] = f2bf(v.w);
        }
    }
    __syncthreads();
    // LN stats from bf16 tile
    {
        const int tok = tid & 63, cl = tid >> 6;
        float s = 0.f, s2 = 0.f;
        #pragma unroll
        for (int g = 0; g < 2; ++g) {
            const ushortx8 u = *(const ushortx8*)&Xb[tok * 72 + cl * 16 + g * 8];
            #pragma unroll
            for (int k = 0; k < 8; ++k) { float v = bf2f(u[k]); s += v; s2 += v * v; }
        }
        red0[cl * 64 + tok] = s; red1[cl * 64 + tok] = s2;
    }
    __syncthreads();
    if (tid < 64) {
        float s  = red0[tid] + red0[64 + tid] + red0[128 + tid] + red0[192 + tid];
        float s2 = red1[tid] + red1[64 + tid] + red1[128 + tid] + red1[192 + tid];
        float mu = s * (1.f / 64.f);
        float var = s2 * (1.f / 64.f) - mu * mu;
        muv[tid] = mu; rsv[tid] = rsqrtf(var + 1e-5f);
    }
    __syncthreads();
    // normalize in place
    #pragma unroll
    for (int it = 0; it < 16; ++it) {
        int tt = wv + 4 * it;
        float v = bf2f(Xb[tt * 72 + lane]);
        v = (v - muv[tt]) * rsv[tt] * lwv[lane] + lbv[lane];
        Xb[tt * 72 + lane] = f2bf(v);
    }
    __syncthreads();

    // MFMA: acc[mt][nt], m = 64wv+16mt (hidden ch), n = 16nt (token), K=64
    f32x4 acc[4][4];
    #pragma unroll
    for (int mt = 0; mt < 4; ++mt)
        #pragma unroll
        for (int nt = 0; nt < 4; ++nt) acc[mt][nt] = zz;
    #pragma unroll
    for (int s = 0; s < 2; ++s) {
        bf16x8 Bf[4];
        #pragma unroll
        for (int nt = 0; nt < 4; ++nt)
            Bf[nt] = *(const bf16x8*)&Xb[(nt * 16 + l15) * 72 + s * 32 + quad * 8];
        #pragma unroll
        for (int mt = 0; mt < 4; ++mt) {
            bf16x8 Af = *(const bf16x8*)&Wb[(64 * wv + 16 * mt + l15) * 72 + s * 32 + quad * 8];
            #pragma unroll
            for (int nt = 0; nt < 4; ++nt)
                acc[mt][nt] = __builtin_amdgcn_mfma_f32_16x16x32_bf16(Af, Bf[nt], acc[mt][nt], 0, 0, 0);
        }
    }

    // epilogue: bias + gelu + fp8, direct store (row = hidden ch, col = token)
    #pragma unroll
    for (int mt = 0; mt < 4; ++mt) {
        #pragma unroll
        for (int r = 0; r < 4; ++r) {
            const int mch = 64 * wv + 16 * mt + quad * 4 + r;
            const float bias = fb[mch];
            unsigned char* Dp = D + (((size_t)(b * 256 + mch)) << 16) + y * 256 + x0;
            #pragma unroll
            for (int nt = 0; nt < 4; ++nt) {
                float v = acc[mt][nt][r] + bias;
                Dp[nt * 16 + l15] = f32_to_fp8(gelu_f(v));
            }
        }
    }
}

// ---------------------------------------------------------------------------
// Kernel 4: depthwise 5x5 conv + GELU + residual add (image layout, fp8).
// 4 x-adjacent outputs/thread; two aligned float4 LDS loads per tap-row.
// ---------------------------------------------------------------------------
__global__ __launch_bounds__(256) void k_dwconv(const unsigned char* __restrict__ D,
        const float* __restrict__ dww, const float* __restrict__ dwb,
        unsigned char* __restrict__ E) {
    __shared__ float sm[20 * 68];
    const int tid = threadIdx.x, gid = blockIdx.x;
    const int xt = gid & 3, yt = (gid >> 2) & 15, pc = gid >> 6;
    const int ch = pc & 255;
    const int x0 = xt * 64, y0 = yt * 16;
    const unsigned char* Dp = D + ((size_t)pc << 16);
    for (int idx = tid; idx < 20 * 68; idx += 256) {
        int r = idx / 68, cc = idx - r * 68;
        int gy = y0 + r - 2, gx = x0 + cc - 2;
        float v = 0.f;
        if (gy >= 0 && gy < 256 && gx >= 0 && gx < 256)
            v = fp8_to_f32(Dp[gy * 256 + gx]);
        sm[idx] = v;
    }
    float wr[25];
    #pragma unroll
    for (int k = 0; k < 25; ++k) wr[k] = dww[ch * 25 + k];   // block-uniform
    const float bb = dwb[ch];
    __syncthreads();
    const int xq = tid & 15, yl = tid >> 4;     // output (y0+yl, x0+4xq..+3)
    float a0 = bb, a1 = bb, a2 = bb, a3 = bb;
    float c0 = 0.f, c1 = 0.f, c2 = 0.f, c3 = 0.f;
    #pragma unroll
    for (int ky = 0; ky < 5; ++ky) {
        const float* rowp = &sm[(yl + ky) * 68 + 4 * xq];
        float4 lo = *(const float4*)rowp;
        float4 hi = *(const float4*)(rowp + 4);
        float v[8] = {lo.x, lo.y, lo.z, lo.w, hi.x, hi.y, hi.z, hi.w};
        if (ky == 2) { c0 = v[2]; c1 = v[3]; c2 = v[4]; c3 = v[5]; }
        #pragma unroll
        for (int kx = 0; kx < 5; ++kx) {
            const float w = wr[ky * 5 + kx];
            a0 += w * v[kx];     a1 += w * v[kx + 1];
            a2 += w * v[kx + 2]; a3 += w * v[kx + 3];
        }
    }
    uchar4 o;
    o.x = f32_to_fp8(c0 + gelu_f(a0));
    o.y = f32_to_fp8(c1 + gelu_f(a1));
    o.z = f32_to_fp8(c2 + gelu_f(a2));
    o.w = f32_to_fp8(c3 + gelu_f(a3));
    *(uchar4*)&E[((size_t)pc << 16) + (y0 + yl) * 256 + x0 + 4 * xq] = o;
}

// ---------------------------------------------------------------------------
// Kernel 5: fc2 + bias + residual + transpose -> out (b,c,h,w) fp32, MFMA.
// A = fc2w (m = 64 oc), B = hid (n = 64 tokens) => C col = token: direct
// coalesced fp32 stores. K=256 in 2 chunks of 128; hid transposed into LDS
// with granule-XOR swizzle (g ^= tok>>2) -> <=2-way conflicts on both sides.
// ---------------------------------------------------------------------------
__global__ __launch_bounds__(256) void k_fc2(const unsigned char* __restrict__ E,
        const unsigned short* __restrict__ Cb, const float* __restrict__ fc2w,
        const float* __restrict__ fc2b, float* __restrict__ out) {
    __shared__ __align__(16) unsigned short Hb[64 * 136];   // [tok][k128 swz]
    __shared__ __align__(16) unsigned short Wb2[64 * 264];  // [oc][k256]
    __shared__ __align__(16) unsigned short Cl[64 * 72];    // residual raw bf16
    __shared__ float fbl[64];
    const int tid = threadIdx.x, gid = blockIdx.x;
    const int xc = gid & 3, y = (gid >> 2) & 255, b = gid >> 10;
    const int x0 = xc * 64;
    const int lane = tid & 63, wv = tid >> 6;
    const int l15 = lane & 15, quad = lane >> 4;
    const f32x4 zz = {0.f, 0.f, 0.f, 0.f};

    if (tid < 64) fbl[tid] = fc2b[tid];
    // stage residual (raw bf16 copy, coalesced)
    {
        const unsigned short* Cp = Cb + ((size_t)(b << 16) + y * 256 + x0) * 64;
        #pragma unroll
        for (int it = 0; it < 16; ++it) {
            int tt = wv + 4 * it;
            Cl[tt * 72 + lane] = Cp[tt * 64 + lane];
        }
    }
    // stage fc2w -> bf16
    {
        const float4* w4 = (const float4*)fc2w;
        #pragma unroll
        for (int it = 0; it < 16; ++it) {
            int idx4 = it * 256 + tid;
            float4 v = w4[idx4];
            int row = idx4 >> 6, c4 = idx4 & 63;
            unsigned short* p = &Wb2[row * 264 + c4 * 4];
            p[0] = f2bf(v.x); p[1] = f2bf(v.y); p[2] = f2bf(v.z); p[3] = f2bf(v.w);
        }
    }

    f32x4 acc[4];
    #pragma unroll
    for (int nt = 0; nt < 4; ++nt) acc[nt] = zz;

    const int ldc = tid >> 4;           // 0..15: channel sub-index for loads
    const int tq  = tid & 15;           // token quad
    uchar4 u0[8];
    // prefetch chunk 0
    #pragma unroll
    for (int it = 0; it < 8; ++it) {
        int chl = ldc + 16 * it;        // 0..127
        u0[it] = *(const uchar4*)&E[(((size_t)(b * 256 + chl)) << 16) + y * 256 + x0 + 4 * tq];
    }
    __syncthreads();                    // Cl, Wb2 visible

    for (int kc = 0; kc < 2; ++kc) {
        // scatter chunk into Hb with granule swizzle
        #pragma unroll
        for (int it = 0; it < 8; ++it) {
            int chl = ldc + 16 * it;
            uchar4 u = u0[it];
            #pragma unroll
            for (int j = 0; j < 4; ++j) {
                int tok = 4 * tq + j;
                unsigned char uv = (j == 0) ? u.x : (j == 1) ? u.y : (j == 2) ? u.z : u.w;
                int pos = (((chl >> 3) ^ (tok >> 2)) << 3) + (chl & 7);
                Hb[tok * 136 + pos] = f2bf(fp8_to_f32(uv));
            }
        }
        // prefetch chunk 1 while chunk 0 computes
        if (kc == 0) {
            #pragma unroll
            for (int it = 0; it < 8; ++it) {
                int chl = ldc + 16 * it + 128;
                u0[it] = *(const uchar4*)&E[(((size_t)(b * 256 + chl)) << 16) + y * 256 + x0 + 4 * tq];
            }
        }
        __syncthreads();
        // MFMA over this 128-K chunk
        #pragma unroll
        for (int k32 = 0; k32 < 4; ++k32) {
            bf16x8 Af = *(const bf16x8*)&Wb2[(16 * wv + l15) * 264 + kc * 128 + k32 * 32 + quad * 8];
            const int g = k32 * 4 + quad;
            #pragma unroll
            for (int nt = 0; nt < 4; ++nt) {
                const int tok = nt * 16 + l15;
                bf16x8 Bf = *(const bf16x8*)&Hb[tok * 136 + ((g ^ (tok >> 2)) << 3)];
                acc[nt] = __builtin_amdgcn_mfma_f32_16x16x32_bf16(Af, Bf, acc[nt], 0, 0, 0);
            }
        }
        if (kc == 0) __syncthreads();   // before overwriting Hb
    }

    // epilogue: bias + residual, direct fp32 store (row = oc, col = token)
    #pragma unroll
    for (int r = 0; r < 4; ++r) {
        const int oc = 16 * wv + quad * 4 + r;
        const float bias = fbl[oc];
        float* op = out + (((size_t)(b * 64 + oc)) << 16) + y * 256 + x0;
        #pragma unroll
        for (int nt = 0; nt < 4; ++nt) {
            const int tok = nt * 16 + l15;
            op[tok] = acc[nt][r] + bias + bf2f(Cl[tok * 72 + oc]);
        }
    }
}

// ---------------------------------------------------------------------------
extern "C" void kernel_launch(void* const* d_in, const int* in_sizes, int n_in,
                              void* d_out, int out_size, void* d_ws, size_t ws_size,
                              hipStream_t stream) {
    const float* x     = (const float*)d_in[0];
    const float* n1w   = (const float*)d_in[1];
    const float* n1b   = (const float*)d_in[2];
    const float* qkvw  = (const float*)d_in[3];
    const float* qkvb  = (const float*)d_in[4];
    const float* rpb   = (const float*)d_in[5];
    const float* projw = (const float*)d_in[6];
    const float* projb = (const float*)d_in[7];
    const float* n2w   = (const float*)d_in[8];
    const float* n2b   = (const float*)d_in[9];
    const float* fc1w  = (const float*)d_in[10];
    const float* fc1b  = (const float*)d_in[11];
    const float* dww   = (const float*)d_in[12];
    const float* dwb   = (const float*)d_in[13];
    const float* fc2w  = (const float*)d_in[14];
    const float* fc2b  = (const float*)d_in[15];
    float* out = (float*)d_out;

    char* ws = (char*)d_ws;
    const size_t MB = 1048576;
    unsigned short* Cbuf = (unsigned short*)ws;                  // [0,32M)
    unsigned short* Ab   = (unsigned short*)(ws + 32 * MB);      // [32,64M)
    unsigned short* Bwp  = (unsigned short*)(ws + 64 * MB);      // [64,96M)
    unsigned char*  Dh   = (unsigned char*)(ws + 32 * MB);       // [32,96M)  alias A+Bw
    unsigned char*  Eh   = (unsigned char*)(ws + 96 * MB);       // [96,160M)

    k_ln1   <<<4096,  256, 0, stream>>>(x, n1w, n1b, Ab, Bwp);
    k_attn  <<<4096,  256, 0, stream>>>(Bwp, qkvw, qkvb, rpb, projw, projb, Ab, Cbuf);
    k_ln2fc1<<<4096,  256, 0, stream>>>(Cbuf, n2w, n2b, fc1w, fc1b, Dh);
    k_dwconv<<<65536, 256, 0, stream>>>(Dh, dww, dwb, Eh);
    k_fc2   <<<4096,  256, 0, stream>>>(Eh, Cbuf, fc2w, fc2b, out);
}